// Round 5
// baseline (236.528 us; speedup 1.0000x reference)
//
#include <hip/hip_runtime.h>
#include <cstdint>

typedef __attribute__((ext_vector_type(8))) short short8;
typedef __attribute__((ext_vector_type(4))) float floatx4;

__device__ __forceinline__ unsigned short f2bf(float f) {
  uint32_t u = __builtin_bit_cast(uint32_t, f);
  u += 0x7fffu + ((u >> 16) & 1u);   // RNE
  return (unsigned short)(u >> 16);
}
// pack bf16(lo)|bf16(hi)<<16, round-half-up: 2 adds + 1 v_perm
__device__ __forceinline__ uint32_t pkbf(float lo, float hi) {
  uint32_t a = __builtin_bit_cast(uint32_t, lo) + 0x8000u;
  uint32_t b = __builtin_bit_cast(uint32_t, hi) + 0x8000u;
  return __builtin_amdgcn_perm(b, a, 0x07060302);
}
// async global->LDS, 16B per lane (HW: wave-uniform LDS base + lane*16)
__device__ __forceinline__ void gll16(const void* g, void* l) {
  __builtin_amdgcn_global_load_lds(
      (const __attribute__((address_space(1))) unsigned int*)g,
      (__attribute__((address_space(3))) unsigned int*)l, 16, 0, 0);
}

// ---------------- kernel 1: build Wt LDS-image (fp32 -> bf16, swizzled) --------
// Image chunk order == the linear order global_load_lds writes LDS in proj:
// [bz(3)][kb(24)][row(192)][cs(4)] 16B chunks; chunk cs holds data k-chunk
// c = cs ^ ((row>>1)&3)  (XOR bank swizzle baked into the image).
__global__ void prep_w_kernel(const float* __restrict__ Wq,
                              const float* __restrict__ Wk,
                              const float* __restrict__ Wv,
                              unsigned short* __restrict__ Wt) {
  int id = blockIdx.x * 256 + threadIdx.x;      // 55296 chunks total
  int bz = id / 18432, rem = id - bz * 18432;
  int kb = rem / 768, s = rem - kb * 768;
  int row = s >> 2, cs = s & 3;                  // row = output col nn 0..191
  int c = cs ^ ((row >> 1) & 3);
  const float* W = (bz == 0) ? Wq : (bz == 1) ? Wk : Wv;
  int k0 = kb * 32 + c * 8;
  unsigned short v[8];
#pragma unroll
  for (int e = 0; e < 8; ++e) v[e] = f2bf(W[(size_t)(k0 + e) * 192 + row]);
  uint4 o;
  o.x = v[0] | ((uint32_t)v[1] << 16);
  o.y = v[2] | ((uint32_t)v[3] << 16);
  o.z = v[4] | ((uint32_t)v[5] << 16);
  o.w = v[6] | ((uint32_t)v[7] << 16);
  *(uint4*)(Wt + (size_t)id * 8) = o;
}

// ---------------- kernel 2: QKV projection + RoPE (v4) ----------------
// grid (512 m-tiles, 3 which). Block: 64 rows x 192 cols, BK=32, 4 waves.
// v3 post-mortem: DMA/A-prefetch still drained by the vmcnt(0)-before-barrier
// (m97 stall); only other resident blocks hide it (m114) and we had 2.35/CU.
// v4: shrink tile 288->192 cols -> LDS 32KB -> 5 blocks/CU resident
// (launch_bounds(256,5), VGPR cap ~96; acc[2][6]=48 regs, v3 fit 9 ntiles in 80).
// Staging: exactly 3 full-wave gll16/thread. x read 3x -> L3 absorbs (r0 data).
__global__ __launch_bounds__(256, 5) void proj_kernel(
    const float* __restrict__ x, const unsigned short* __restrict__ Wt,
    unsigned short* __restrict__ q_ws, unsigned short* __restrict__ k_ws,
    unsigned short* __restrict__ v_ws) {
  __shared__ __align__(16) unsigned short A_lds[2][64 * 32];    // 2 x 4KB
  __shared__ __align__(16) unsigned short B_lds[2][192 * 32];   // 2 x 12KB
  const int tid = threadIdx.x;
  const int w = tid >> 6, l = tid & 63, quad = l >> 4, ln = l & 15;
  const int wr = w & 1, wc = w >> 1;
  const int m0 = blockIdx.x * 64;
  const int bz = blockIdx.y;

  // A staging: thread -> one 16B chunk (8 bf16) of one row
  const int arow = tid >> 2, ac = tid & 3;
  const int aslot = ((ac ^ ((arow >> 1) & 3)) << 4);
  const float* xp = x + (size_t)(m0 + arow) * 768 + ac * 8;
  // B image for this which: 18432 chunks
  const unsigned short* wimg = Wt + (size_t)bz * 18432 * 8;

  // fragment read chunk: (row>>1)&3 == (ln>>1)&3 for all frag rows (bases %8==0)
  const int fq = ((quad ^ ((ln >> 1) & 3)) << 4);

  floatx4 acc[2][6];
#pragma unroll
  for (int mi = 0; mi < 2; ++mi)
#pragma unroll
    for (int nj = 0; nj < 6; ++nj) acc[mi][nj] = floatx4{0.f, 0.f, 0.f, 0.f};

  float4 a0x, a0y;

#define LOADA(K0)                                  \
  do {                                             \
    a0x = *(const float4*)(xp + (K0));             \
    a0y = *(const float4*)(xp + (K0) + 4);         \
  } while (0)
#define STAGEA(BUF)                                               \
  do {                                                            \
    uint4 ap;                                                     \
    ap.x = pkbf(a0x.x, a0x.y);                                    \
    ap.y = pkbf(a0x.z, a0x.w);                                    \
    ap.z = pkbf(a0y.x, a0y.y);                                    \
    ap.w = pkbf(a0y.z, a0y.w);                                    \
    *(uint4*)((char*)&A_lds[BUF][0] + arow * 64 + aslot) = ap;    \
  } while (0)
#define LOADB(KB, BUF)                                               \
  do {                                                               \
    const unsigned short* src = wimg + (size_t)(KB) * 6144;          \
    char* dstb = (char*)&B_lds[BUF][0];                              \
    _Pragma("unroll") for (int it = 0; it < 3; ++it)                 \
        gll16(src + (it * 256 + tid) * 8, dstb + (it * 256 + tid) * 16); \
  } while (0)
#define PCOMPUTE(BUF)                                                            \
  do {                                                                           \
    short8 af0 = *(const short8*)((const char*)&A_lds[BUF][0] +                  \
                                  (wr * 32 + ln) * 64 + fq);                     \
    short8 af1 = *(const short8*)((const char*)&A_lds[BUF][0] +                  \
                                  (wr * 32 + 16 + ln) * 64 + fq);                \
    _Pragma("unroll") for (int nj = 0; nj < 6; ++nj) {                           \
      short8 bf = *(const short8*)((const char*)&B_lds[BUF][0] +                 \
                                   (wc * 96 + nj * 16 + ln) * 64 + fq);          \
      acc[0][nj] = __builtin_amdgcn_mfma_f32_16x16x32_bf16(af0, bf, acc[0][nj],  \
                                                           0, 0, 0);             \
      acc[1][nj] = __builtin_amdgcn_mfma_f32_16x16x32_bf16(af1, bf, acc[1][nj],  \
                                                           0, 0, 0);             \
    }                                                                            \
  } while (0)

  // prologue
  LOADB(0, 0);
  LOADA(0);
  STAGEA(0);
  LOADA(32);
  __syncthreads();  // drains B(0) DMA + A(1) regs

#pragma unroll 2
  for (int kb = 0; kb < 24; ++kb) {
    const int cur = kb & 1, nxt = cur ^ 1;
    if (kb < 23) {
      LOADB(kb + 1, nxt);   // async DMA into other buffer, hidden under compute
      STAGEA(nxt);          // a0 holds kb+1 data (loaded 1 phase ago)
    }
    if (kb < 22) LOADA((kb + 2) * 32);  // HBM/L3 latency hidden under MFMA phase
    PCOMPUTE(cur);
    __syncthreads();
  }
#undef LOADA
#undef STAGEA
#undef LOADB
#undef PCOMPUTE

  // epilogue. global col n = wc*96 + nj*16 + ln within 'which' bz.
  // role = bz*2+wc: 0: Q0..95 (RoPE nj0,1) | 1: Q96..191
  //                 2: K0..95 (RoPE nj0,1) | 3: K96..191
  //                 4: V0..95 | 5: V96..191 (V stored transposed [b][dim][t])
  const float R_LG = 0.8304820237218406f;  // log2(10000)/16
#define ROPE2(V0, V1, TPOS)                                         \
  do {                                                              \
    float i0 = (float)(ln >> 1);                                    \
    float f0 = exp2f(-i0 * R_LG);                                   \
    float f1 = exp2f(-(i0 + 8.0f) * R_LG);                          \
    float s0, c0, s1, c1;                                           \
    sincosf((float)(TPOS)*f0, &s0, &c0);                            \
    sincosf((float)(TPOS)*f1, &s1, &c1);                            \
    float p0 = __shfl_xor(V0, 1), p1 = __shfl_xor(V1, 1);           \
    V0 = (ln & 1) ? (V0 * c0 + p0 * s0) : (V0 * c0 - p0 * s0);      \
    V1 = (ln & 1) ? (V1 * c1 + p1 * s1) : (V1 * c1 - p1 * s1);      \
  } while (0)

  if (bz < 2) {
    unsigned short* dst = (bz == 0) ? q_ws : k_ws;
    if (wc == 0) {
#pragma unroll
      for (int mi = 0; mi < 2; ++mi)
#pragma unroll
        for (int r = 0; r < 4; ++r) {
          int row_g = m0 + wr * 32 + mi * 16 + quad * 4 + r;
          int t_pos = row_g & 511;
          float v0 = acc[mi][0][r], v1 = acc[mi][1][r];
          ROPE2(v0, v1, t_pos);
          dst[(size_t)row_g * 192 + ln] = f2bf(v0);
          dst[(size_t)row_g * 192 + 16 + ln] = f2bf(v1);
#pragma unroll
          for (int nj = 2; nj < 6; ++nj)
            dst[(size_t)row_g * 192 + nj * 16 + ln] = f2bf(acc[mi][nj][r]);
        }
    } else {
#pragma unroll
      for (int mi = 0; mi < 2; ++mi)
#pragma unroll
        for (int r = 0; r < 4; ++r) {
          int row_g = m0 + wr * 32 + mi * 16 + quad * 4 + r;
#pragma unroll
          for (int nj = 0; nj < 6; ++nj)
            dst[(size_t)row_g * 192 + 96 + nj * 16 + ln] = f2bf(acc[mi][nj][r]);
        }
    }
  } else {
    const int dbase = wc * 96;
#pragma unroll
    for (int mi = 0; mi < 2; ++mi) {
      int rb = m0 + wr * 32 + mi * 16 + quad * 4;  // 4 consecutive rows, same batch
      int bb = rb >> 9, t = rb & 511;
#pragma unroll
      for (int nj = 0; nj < 6; ++nj) {
        ushort4 pv;
        pv.x = f2bf(acc[mi][nj][0]);
        pv.y = f2bf(acc[mi][nj][1]);
        pv.z = f2bf(acc[mi][nj][2]);
        pv.w = f2bf(acc[mi][nj][3]);
        *(ushort4*)&v_ws[((size_t)bb * 192 + dbase + nj * 16 + ln) * 512 + t] = pv;
      }
    }
  }
#undef ROPE2
}

// ---------------- kernel 3: causal flash attention (MFMA) ----------------
// grid (8, 64). qt remap: dispatch i and i+256 carry complementary qt
// (CU pair sums to 9 K-tiles). v1 structure (known-good) + s_setprio (T5).
// UNCHANGED from the passing round-4 version.
__global__ __launch_bounds__(256) void attn_kernel(
    const unsigned short* __restrict__ q_ws, const unsigned short* __restrict__ k_ws,
    const unsigned short* __restrict__ v_ws, float* __restrict__ out) {
  __shared__ __align__(16) unsigned short K_lds[64 * 200];
  __shared__ __align__(16) unsigned short V_lds[192 * 72];   // V^T: [dim][key]
  __shared__ __align__(16) unsigned short P_lds[4][16 * 72]; // per-wave P
  const int tid = threadIdx.x;
  const int w = tid >> 6, l = tid & 63, quad = l >> 4, ln = l & 15;
  const int b = blockIdx.y;
  const int qt = (blockIdx.y < 32) ? blockIdx.x : 7 - blockIdx.x;
  const int q0 = qt * 64;

  // preload Q A-fragments
  short8 qf[6];
  {
    const unsigned short* qp =
        q_ws + (size_t)(b * 512 + q0 + w * 16 + ln) * 192 + quad * 8;
#pragma unroll
    for (int kk = 0; kk < 6; ++kk) qf[kk] = *(const short8*)(qp + kk * 32);
  }

  float m_i[4], l_i[4];
  floatx4 o[12];
#pragma unroll
  for (int r = 0; r < 4; ++r) { m_i[r] = -1e30f; l_i[r] = 0.f; }
#pragma unroll
  for (int nt = 0; nt < 12; ++nt) o[nt] = floatx4{0.f, 0.f, 0.f, 0.f};
  const float sm_scale = 0.07216878364870323f;  // 192^-0.5

  for (int kt = 0; kt <= qt; ++kt) {
    const int k0 = kt * 64;
    __syncthreads();  // previous iteration's LDS reads done before overwrite
    // stage K tile [64][192]
#pragma unroll
    for (int it = 0; it < 6; ++it) {
      int idx = it * 256 + tid;
      int row = idx / 24, c = idx - row * 24;
      uint4 v = *(const uint4*)(k_ws + (size_t)(b * 512 + k0 + row) * 192 + c * 8);
      *(uint4*)&K_lds[row * 200 + c * 8] = v;
    }
    // stage V^T tile [192][64]
#pragma unroll
    for (int it = 0; it < 6; ++it) {
      int idx = it * 256 + tid;
      int row = idx >> 3, c = idx & 7;
      uint4 v = *(const uint4*)(v_ws + (size_t)(b * 192 + row) * 512 + k0 + c * 8);
      *(uint4*)&V_lds[row * 72 + c * 8] = v;
    }
    __syncthreads();

    // S = Q K^T (scaled)
    float s[4][4];
    __builtin_amdgcn_s_setprio(1);
#pragma unroll
    for (int nt = 0; nt < 4; ++nt) {
      floatx4 sa = floatx4{0.f, 0.f, 0.f, 0.f};
#pragma unroll
      for (int kk = 0; kk < 6; ++kk) {
        short8 kf = *(const short8*)&K_lds[(nt * 16 + ln) * 200 + kk * 32 + quad * 8];
        sa = __builtin_amdgcn_mfma_f32_16x16x32_bf16(qf[kk], kf, sa, 0, 0, 0);
      }
#pragma unroll
      for (int r = 0; r < 4; ++r) s[nt][r] = sa[r] * sm_scale;
    }
    __builtin_amdgcn_s_setprio(0);
    if (kt == qt) {  // diagonal tile mask (k0 == q0)
#pragma unroll
      for (int nt = 0; nt < 4; ++nt)
#pragma unroll
        for (int r = 0; r < 4; ++r)
          if (nt * 16 + ln > w * 16 + quad * 4 + r) s[nt][r] = -1e30f;
    }
    // online softmax (row = quad*4+r)
    float alpha[4];
#pragma unroll
    for (int r = 0; r < 4; ++r) {
      float mx = fmaxf(fmaxf(s[0][r], s[1][r]), fmaxf(s[2][r], s[3][r]));
      mx = fmaxf(mx, __shfl_xor(mx, 1));
      mx = fmaxf(mx, __shfl_xor(mx, 2));
      mx = fmaxf(mx, __shfl_xor(mx, 4));
      mx = fmaxf(mx, __shfl_xor(mx, 8));
      float mnew = fmaxf(m_i[r], mx);
      alpha[r] = __expf(m_i[r] - mnew);
      float sum = 0.f;
#pragma unroll
      for (int nt = 0; nt < 4; ++nt) {
        s[nt][r] = __expf(s[nt][r] - mnew);
        sum += s[nt][r];
      }
      sum += __shfl_xor(sum, 1);
      sum += __shfl_xor(sum, 2);
      sum += __shfl_xor(sum, 4);
      sum += __shfl_xor(sum, 8);
      l_i[r] = l_i[r] * alpha[r] + sum;
      m_i[r] = mnew;
    }
#pragma unroll
    for (int nt = 0; nt < 12; ++nt)
#pragma unroll
      for (int r = 0; r < 4; ++r) o[nt][r] *= alpha[r];

    // P: C/D layout -> A layout via per-wave LDS
#pragma unroll
    for (int nt = 0; nt < 4; ++nt)
#pragma unroll
      for (int r = 0; r < 4; ++r)
        P_lds[w][(quad * 4 + r) * 72 + nt * 16 + ln] = f2bf(s[nt][r]);
    __asm__ volatile("s_waitcnt lgkmcnt(0)" ::: "memory");  // wave-local write->read

    // O += P V
    __builtin_amdgcn_s_setprio(1);
#pragma unroll
    for (int ks = 0; ks < 2; ++ks) {
      short8 pf = *(const short8*)&P_lds[w][ln * 72 + ks * 32 + quad * 8];
#pragma unroll
      for (int nt = 0; nt < 12; ++nt) {
        short8 vf = *(const short8*)&V_lds[(nt * 16 + ln) * 72 + ks * 32 + quad * 8];
        o[nt] = __builtin_amdgcn_mfma_f32_16x16x32_bf16(pf, vf, o[nt], 0, 0, 0);
      }
    }
    __builtin_amdgcn_s_setprio(0);
  }

  // epilogue: O/l -> fp32 out [b][t][dim]
#pragma unroll
  for (int r = 0; r < 4; ++r) {
    float inv = 1.0f / l_i[r];
    size_t rowoff = (size_t)(b * 512 + q0 + w * 16 + quad * 4 + r) * 192;
#pragma unroll
    for (int nt = 0; nt < 12; ++nt)
      out[rowoff + nt * 16 + ln] = o[nt][r] * inv;
  }
}

extern "C" void kernel_launch(void* const* d_in, const int* in_sizes, int n_in,
                              void* d_out, int out_size, void* d_ws, size_t ws_size,
                              hipStream_t stream) {
  const float* x = (const float*)d_in[0];
  const float* Wq = (const float*)d_in[1];
  const float* Wk = (const float*)d_in[2];
  const float* Wv = (const float*)d_in[3];
  float* out = (float*)d_out;

  char* ws = (char*)d_ws;
  const size_t QKV_BYTES = (size_t)64 * 512 * 192 * 2;  // 12,582,912
  unsigned short* q_ws = (unsigned short*)(ws);
  unsigned short* k_ws = (unsigned short*)(ws + QKV_BYTES);
  unsigned short* v_ws = (unsigned short*)(ws + 2 * QKV_BYTES);
  unsigned short* Wt = (unsigned short*)(ws + 3 * QKV_BYTES);  // 884,736 B image

  hipLaunchKernelGGL(prep_w_kernel, dim3(216), dim3(256), 0, stream, Wq, Wk, Wv, Wt);
  hipLaunchKernelGGL(proj_kernel, dim3(512, 3), dim3(256), 0, stream, x, Wt, q_ws, k_ws, v_ws);
  hipLaunchKernelGGL(attn_kernel, dim3(8, 64), dim3(256), 0, stream, q_ws, k_ws, v_ws, out);
}

// Round 6
// 222.506 us; speedup vs baseline: 1.0630x; 1.0630x over previous
//
#include <hip/hip_runtime.h>
#include <cstdint>

typedef __attribute__((ext_vector_type(8))) short short8;
typedef __attribute__((ext_vector_type(4))) float floatx4;

__device__ __forceinline__ unsigned short f2bf(float f) {
  uint32_t u = __builtin_bit_cast(uint32_t, f);
  u += 0x7fffu + ((u >> 16) & 1u);   // RNE
  return (unsigned short)(u >> 16);
}
// pack bf16(lo)|bf16(hi)<<16, round-half-up: 2 adds + 1 v_perm
__device__ __forceinline__ uint32_t pkbf(float lo, float hi) {
  uint32_t a = __builtin_bit_cast(uint32_t, lo) + 0x8000u;
  uint32_t b = __builtin_bit_cast(uint32_t, hi) + 0x8000u;
  return __builtin_amdgcn_perm(b, a, 0x07060302);
}
// async global->LDS, 16B per lane (HW: wave-uniform LDS base + lane*16)
__device__ __forceinline__ void gll16(const void* g, void* l) {
  __builtin_amdgcn_global_load_lds(
      (const __attribute__((address_space(1))) unsigned int*)g,
      (__attribute__((address_space(3))) unsigned int*)l, 16, 0, 0);
}

// ---------------- kernel 1: build Wt LDS-image (fp32 -> bf16, swizzled) --------
// Image chunk order == the linear order global_load_lds writes LDS in proj:
// [bz(3)][kb(24)][row(192)][cs(4)] 16B chunks; chunk cs holds data k-chunk
// c = cs ^ ((row>>1)&3)  (XOR bank swizzle baked into the image).
__global__ void prep_w_kernel(const float* __restrict__ Wq,
                              const float* __restrict__ Wk,
                              const float* __restrict__ Wv,
                              unsigned short* __restrict__ Wt) {
  int id = blockIdx.x * 256 + threadIdx.x;      // 55296 chunks total
  int bz = id / 18432, rem = id - bz * 18432;
  int kb = rem / 768, s = rem - kb * 768;
  int row = s >> 2, cs = s & 3;                  // row = output col nn 0..191
  int c = cs ^ ((row >> 1) & 3);
  const float* W = (bz == 0) ? Wq : (bz == 1) ? Wk : Wv;
  int k0 = kb * 32 + c * 8;
  unsigned short v[8];
#pragma unroll
  for (int e = 0; e < 8; ++e) v[e] = f2bf(W[(size_t)(k0 + e) * 192 + row]);
  uint4 o;
  o.x = v[0] | ((uint32_t)v[1] << 16);
  o.y = v[2] | ((uint32_t)v[3] << 16);
  o.z = v[4] | ((uint32_t)v[5] << 16);
  o.w = v[6] | ((uint32_t)v[7] << 16);
  *(uint4*)(Wt + (size_t)id * 8) = o;
}

// ---------------- kernel 2: QKV projection + RoPE (v5) ----------------
// v4 post-mortem: per-K-iter cost ~830-2000cy = one full vmcnt(0) drain per
// __syncthreads (m97 stall); occupancy pinned ~30% regardless of LDS.
// v5 = T3/T4 port: counted s_waitcnt vmcnt(N) + raw s_barrier in ONE asm
// block (memory clobber fences both sides); 3-buffer rotation on A and B so
// one barrier/iter is race-free (buffer reuse is 3 iters = 2 barriers apart;
// a wave's ds_reads of iter k are lgkm-complete before it reaches barrier k+1).
// Steady state waits: DMA 1 iter old (~350cy cover, Wt L2-hot), A-load 2
// iters old (~700cy cover, x HBM stream). vmcnt ledger simulated for all 24
// iters: uniform 7, tail 5/3/0.
__global__ __launch_bounds__(256, 3) void proj_kernel(
    const float* __restrict__ x, const unsigned short* __restrict__ Wt,
    unsigned short* __restrict__ q_ws, unsigned short* __restrict__ k_ws,
    unsigned short* __restrict__ v_ws) {
  __shared__ __align__(16) unsigned short A_lds[3][64 * 32];    // 3 x 4KB
  __shared__ __align__(16) unsigned short B_lds[3][192 * 32];   // 3 x 12KB
  const int tid = threadIdx.x;
  const int w = tid >> 6, l = tid & 63, quad = l >> 4, ln = l & 15;
  const int wr = w & 1, wc = w >> 1;
  const int m0 = blockIdx.x * 64;
  const int bz = blockIdx.y;

  // A staging: thread -> one 16B chunk (8 bf16) of one row
  const int arow = tid >> 2, ac = tid & 3;
  const int aslot = ((ac ^ ((arow >> 1) & 3)) << 4);
  const float* xp = x + (size_t)(m0 + arow) * 768 + ac * 8;
  // B image for this which: 18432 chunks
  const unsigned short* wimg = Wt + (size_t)bz * 18432 * 8;

  // fragment read chunk: (row>>1)&3 == (ln>>1)&3 for all frag rows (bases %8==0)
  const int fq = ((quad ^ ((ln >> 1) & 3)) << 4);

  floatx4 acc[2][6];
#pragma unroll
  for (int mi = 0; mi < 2; ++mi)
#pragma unroll
    for (int nj = 0; nj < 6; ++nj) acc[mi][nj] = floatx4{0.f, 0.f, 0.f, 0.f};

  float4 ax0, ay0, ax1, ay1, ax2, ay2;  // 3 rotating A-prefetch reg sets

#define LOADA(S, K0)                               \
  do {                                             \
    ax##S = *(const float4*)(xp + (K0));           \
    ay##S = *(const float4*)(xp + (K0) + 4);       \
  } while (0)
#define STAGEA(S, AB)                                             \
  do {                                                            \
    uint4 ap;                                                     \
    ap.x = pkbf(ax##S.x, ax##S.y);                                \
    ap.y = pkbf(ax##S.z, ax##S.w);                                \
    ap.z = pkbf(ay##S.x, ay##S.y);                                \
    ap.w = pkbf(ay##S.z, ay##S.w);                                \
    *(uint4*)((char*)&A_lds[AB][0] + arow * 64 + aslot) = ap;     \
  } while (0)
#define DMAB(KB1, BB)                                             \
  do {                                                            \
    const unsigned short* src = wimg + (size_t)(KB1)*6144;        \
    char* dstb = (char*)&B_lds[BB][0];                            \
    gll16(src + tid * 8, dstb + tid * 16);                        \
    gll16(src + (256 + tid) * 8, dstb + (256 + tid) * 16);        \
    gll16(src + (512 + tid) * 8, dstb + (512 + tid) * 16);        \
  } while (0)
// counted wait + raw barrier in ONE asm block: memory ops cannot cross
// either side; each wave waits its own (older-than-N) DMAs, then barrier
// => all waves' DMAs for the buffer about to be read are complete.
#define WAITBAR(N)                                                          \
  asm volatile("s_waitcnt vmcnt(" #N ") lgkmcnt(0)\n\ts_barrier" ::: "memory")
#define PCOMPUTE(C)                                                              \
  do {                                                                           \
    short8 af0 = *(const short8*)((const char*)&A_lds[C][0] +                    \
                                  (wr * 32 + ln) * 64 + fq);                     \
    short8 af1 = *(const short8*)((const char*)&A_lds[C][0] +                    \
                                  (wr * 32 + 16 + ln) * 64 + fq);                \
    _Pragma("unroll") for (int nj = 0; nj < 6; ++nj) {                           \
      short8 bf = *(const short8*)((const char*)&B_lds[C][0] +                   \
                                   (wc * 96 + nj * 16 + ln) * 64 + fq);          \
      acc[0][nj] = __builtin_amdgcn_mfma_f32_16x16x32_bf16(af0, bf, acc[0][nj],  \
                                                           0, 0, 0);             \
      acc[1][nj] = __builtin_amdgcn_mfma_f32_16x16x32_bf16(af1, bf, acc[1][nj],  \
                                                           0, 0, 0);             \
    }                                                                            \
  } while (0)
// BODY(KB): C=KB%3 (compute bufs + A reg set loaded), P=(KB+1)%3 (A reg set
// consumed -> a[P]; DMA -> b[P]). LOADA(KB+3) consumed by STAGEA at KB+2.
#define BODY(KB, C, P)            \
  do {                            \
    STAGEA(P, P);                 \
    DMAB((KB) + 1, P);            \
    LOADA(C, ((KB) + 3) * 32);    \
    WAITBAR(7);                   \
    PCOMPUTE(C);                  \
  } while (0)

  // prologue: DMA k-step 0; A-loads for k-steps 0,1,2; stage a[0]
  DMAB(0, 0);
  LOADA(0, 0);
  LOADA(1, 32);
  LOADA(2, 64);
  STAGEA(0, 0);

  BODY(0, 0, 1);
  for (int t = 1; t <= 16; t += 3) {  // t = 1,4,7,10,13,16 -> iters 1..18
    BODY(t, 1, 2);
    BODY(t + 1, 2, 0);
    BODY(t + 2, 0, 1);
  }
  BODY(19, 1, 2);
  BODY(20, 2, 0);
  // 21: no LOADA (would read past K=768)
  { STAGEA(1, 1); DMAB(22, 1); WAITBAR(5); PCOMPUTE(0); }
  // 22: no LOADA
  { STAGEA(2, 2); DMAB(23, 2); WAITBAR(3); PCOMPUTE(1); }
  // 23: drain
  { WAITBAR(0); PCOMPUTE(2); }

#undef LOADA
#undef STAGEA
#undef DMAB
#undef WAITBAR
#undef PCOMPUTE
#undef BODY

  // epilogue. global col n = wc*96 + nj*16 + ln within 'which' bz.
  // bz 0: Q (RoPE on wc==0 nj0,1) | bz 1: K (RoPE same) | bz 2: V transposed
  const float R_LG = 0.8304820237218406f;  // log2(10000)/16
#define ROPE2(V0, V1, TPOS)                                         \
  do {                                                              \
    float i0 = (float)(ln >> 1);                                    \
    float f0 = exp2f(-i0 * R_LG);                                   \
    float f1 = exp2f(-(i0 + 8.0f) * R_LG);                          \
    float s0, c0, s1, c1;                                           \
    sincosf((float)(TPOS)*f0, &s0, &c0);                            \
    sincosf((float)(TPOS)*f1, &s1, &c1);                            \
    float p0 = __shfl_xor(V0, 1), p1 = __shfl_xor(V1, 1);           \
    V0 = (ln & 1) ? (V0 * c0 + p0 * s0) : (V0 * c0 - p0 * s0);      \
    V1 = (ln & 1) ? (V1 * c1 + p1 * s1) : (V1 * c1 - p1 * s1);      \
  } while (0)

  if (bz < 2) {
    unsigned short* dst = (bz == 0) ? q_ws : k_ws;
    if (wc == 0) {
#pragma unroll
      for (int mi = 0; mi < 2; ++mi)
#pragma unroll
        for (int r = 0; r < 4; ++r) {
          int row_g = m0 + wr * 32 + mi * 16 + quad * 4 + r;
          int t_pos = row_g & 511;
          float v0 = acc[mi][0][r], v1 = acc[mi][1][r];
          ROPE2(v0, v1, t_pos);
          dst[(size_t)row_g * 192 + ln] = f2bf(v0);
          dst[(size_t)row_g * 192 + 16 + ln] = f2bf(v1);
#pragma unroll
          for (int nj = 2; nj < 6; ++nj)
            dst[(size_t)row_g * 192 + nj * 16 + ln] = f2bf(acc[mi][nj][r]);
        }
    } else {
#pragma unroll
      for (int mi = 0; mi < 2; ++mi)
#pragma unroll
        for (int r = 0; r < 4; ++r) {
          int row_g = m0 + wr * 32 + mi * 16 + quad * 4 + r;
#pragma unroll
          for (int nj = 0; nj < 6; ++nj)
            dst[(size_t)row_g * 192 + 96 + nj * 16 + ln] = f2bf(acc[mi][nj][r]);
        }
    }
  } else {
    const int dbase = wc * 96;
#pragma unroll
    for (int mi = 0; mi < 2; ++mi) {
      int rb = m0 + wr * 32 + mi * 16 + quad * 4;  // 4 consecutive rows, same batch
      int bb = rb >> 9, t = rb & 511;
#pragma unroll
      for (int nj = 0; nj < 6; ++nj) {
        ushort4 pv;
        pv.x = f2bf(acc[mi][nj][0]);
        pv.y = f2bf(acc[mi][nj][1]);
        pv.z = f2bf(acc[mi][nj][2]);
        pv.w = f2bf(acc[mi][nj][3]);
        *(ushort4*)&v_ws[((size_t)bb * 192 + dbase + nj * 16 + ln) * 512 + t] = pv;
      }
    }
  }
#undef ROPE2
}

// ---------------- kernel 3: causal flash attention (MFMA) ----------------
// grid (8, 64). qt remap: dispatch i and i+256 carry complementary qt
// (CU pair sums to 9 K-tiles). v1 structure (known-good) + s_setprio (T5).
// UNCHANGED (byte-identical to the passing round-4/5 version).
__global__ __launch_bounds__(256) void attn_kernel(
    const unsigned short* __restrict__ q_ws, const unsigned short* __restrict__ k_ws,
    const unsigned short* __restrict__ v_ws, float* __restrict__ out) {
  __shared__ __align__(16) unsigned short K_lds[64 * 200];
  __shared__ __align__(16) unsigned short V_lds[192 * 72];   // V^T: [dim][key]
  __shared__ __align__(16) unsigned short P_lds[4][16 * 72]; // per-wave P
  const int tid = threadIdx.x;
  const int w = tid >> 6, l = tid & 63, quad = l >> 4, ln = l & 15;
  const int b = blockIdx.y;
  const int qt = (blockIdx.y < 32) ? blockIdx.x : 7 - blockIdx.x;
  const int q0 = qt * 64;

  // preload Q A-fragments
  short8 qf[6];
  {
    const unsigned short* qp =
        q_ws + (size_t)(b * 512 + q0 + w * 16 + ln) * 192 + quad * 8;
#pragma unroll
    for (int kk = 0; kk < 6; ++kk) qf[kk] = *(const short8*)(qp + kk * 32);
  }

  float m_i[4], l_i[4];
  floatx4 o[12];
#pragma unroll
  for (int r = 0; r < 4; ++r) { m_i[r] = -1e30f; l_i[r] = 0.f; }
#pragma unroll
  for (int nt = 0; nt < 12; ++nt) o[nt] = floatx4{0.f, 0.f, 0.f, 0.f};
  const float sm_scale = 0.07216878364870323f;  // 192^-0.5

  for (int kt = 0; kt <= qt; ++kt) {
    const int k0 = kt * 64;
    __syncthreads();  // previous iteration's LDS reads done before overwrite
    // stage K tile [64][192]
#pragma unroll
    for (int it = 0; it < 6; ++it) {
      int idx = it * 256 + tid;
      int row = idx / 24, c = idx - row * 24;
      uint4 v = *(const uint4*)(k_ws + (size_t)(b * 512 + k0 + row) * 192 + c * 8);
      *(uint4*)&K_lds[row * 200 + c * 8] = v;
    }
    // stage V^T tile [192][64]
#pragma unroll
    for (int it = 0; it < 6; ++it) {
      int idx = it * 256 + tid;
      int row = idx >> 3, c = idx & 7;
      uint4 v = *(const uint4*)(v_ws + (size_t)(b * 192 + row) * 512 + k0 + c * 8);
      *(uint4*)&V_lds[row * 72 + c * 8] = v;
    }
    __syncthreads();

    // S = Q K^T (scaled)
    float s[4][4];
    __builtin_amdgcn_s_setprio(1);
#pragma unroll
    for (int nt = 0; nt < 4; ++nt) {
      floatx4 sa = floatx4{0.f, 0.f, 0.f, 0.f};
#pragma unroll
      for (int kk = 0; kk < 6; ++kk) {
        short8 kf = *(const short8*)&K_lds[(nt * 16 + ln) * 200 + kk * 32 + quad * 8];
        sa = __builtin_amdgcn_mfma_f32_16x16x32_bf16(qf[kk], kf, sa, 0, 0, 0);
      }
#pragma unroll
      for (int r = 0; r < 4; ++r) s[nt][r] = sa[r] * sm_scale;
    }
    __builtin_amdgcn_s_setprio(0);
    if (kt == qt) {  // diagonal tile mask (k0 == q0)
#pragma unroll
      for (int nt = 0; nt < 4; ++nt)
#pragma unroll
        for (int r = 0; r < 4; ++r)
          if (nt * 16 + ln > w * 16 + quad * 4 + r) s[nt][r] = -1e30f;
    }
    // online softmax (row = quad*4+r)
    float alpha[4];
#pragma unroll
    for (int r = 0; r < 4; ++r) {
      float mx = fmaxf(fmaxf(s[0][r], s[1][r]), fmaxf(s[2][r], s[3][r]));
      mx = fmaxf(mx, __shfl_xor(mx, 1));
      mx = fmaxf(mx, __shfl_xor(mx, 2));
      mx = fmaxf(mx, __shfl_xor(mx, 4));
      mx = fmaxf(mx, __shfl_xor(mx, 8));
      float mnew = fmaxf(m_i[r], mx);
      alpha[r] = __expf(m_i[r] - mnew);
      float sum = 0.f;
#pragma unroll
      for (int nt = 0; nt < 4; ++nt) {
        s[nt][r] = __expf(s[nt][r] - mnew);
        sum += s[nt][r];
      }
      sum += __shfl_xor(sum, 1);
      sum += __shfl_xor(sum, 2);
      sum += __shfl_xor(sum, 4);
      sum += __shfl_xor(sum, 8);
      l_i[r] = l_i[r] * alpha[r] + sum;
      m_i[r] = mnew;
    }
#pragma unroll
    for (int nt = 0; nt < 12; ++nt)
#pragma unroll
      for (int r = 0; r < 4; ++r) o[nt][r] *= alpha[r];

    // P: C/D layout -> A layout via per-wave LDS
#pragma unroll
    for (int nt = 0; nt < 4; ++nt)
#pragma unroll
      for (int r = 0; r < 4; ++r)
        P_lds[w][(quad * 4 + r) * 72 + nt * 16 + ln] = f2bf(s[nt][r]);
    __asm__ volatile("s_waitcnt lgkmcnt(0)" ::: "memory");  // wave-local write->read

    // O += P V
    __builtin_amdgcn_s_setprio(1);
#pragma unroll
    for (int ks = 0; ks < 2; ++ks) {
      short8 pf = *(const short8*)&P_lds[w][ln * 72 + ks * 32 + quad * 8];
#pragma unroll
      for (int nt = 0; nt < 12; ++nt) {
        short8 vf = *(const short8*)&V_lds[(nt * 16 + ln) * 72 + ks * 32 + quad * 8];
        o[nt] = __builtin_amdgcn_mfma_f32_16x16x32_bf16(pf, vf, o[nt], 0, 0, 0);
      }
    }
    __builtin_amdgcn_s_setprio(0);
  }

  // epilogue: O/l -> fp32 out [b][t][dim]
#pragma unroll
  for (int r = 0; r < 4; ++r) {
    float inv = 1.0f / l_i[r];
    size_t rowoff = (size_t)(b * 512 + q0 + w * 16 + quad * 4 + r) * 192;
#pragma unroll
    for (int nt = 0; nt < 12; ++nt)
      out[rowoff + nt * 16 + ln] = o[nt][r] * inv;
  }
}

extern "C" void kernel_launch(void* const* d_in, const int* in_sizes, int n_in,
                              void* d_out, int out_size, void* d_ws, size_t ws_size,
                              hipStream_t stream) {
  const float* x = (const float*)d_in[0];
  const float* Wq = (const float*)d_in[1];
  const float* Wk = (const float*)d_in[2];
  const float* Wv = (const float*)d_in[3];
  float* out = (float*)d_out;

  char* ws = (char*)d_ws;
  const size_t QKV_BYTES = (size_t)64 * 512 * 192 * 2;  // 12,582,912
  unsigned short* q_ws = (unsigned short*)(ws);
  unsigned short* k_ws = (unsigned short*)(ws + QKV_BYTES);
  unsigned short* v_ws = (unsigned short*)(ws + 2 * QKV_BYTES);
  unsigned short* Wt = (unsigned short*)(ws + 3 * QKV_BYTES);  // 884,736 B image

  hipLaunchKernelGGL(prep_w_kernel, dim3(216), dim3(256), 0, stream, Wq, Wk, Wv, Wt);
  hipLaunchKernelGGL(proj_kernel, dim3(512, 3), dim3(256), 0, stream, x, Wt, q_ws, k_ws, v_ws);
  hipLaunchKernelGGL(attn_kernel, dim3(8, 64), dim3(256), 0, stream, q_ws, k_ws, v_ws, out);
}